// Round 2
// baseline (1391.251 us; speedup 1.0000x reference)
//
#include <hip/hip_runtime.h>
#include <hip/hip_bf16.h>

// Problem: Conv_SelfAttn — B=8, C=128, N=64*64=4096, C_QK=16.
// All inputs/outputs are FP32 (per reference setup_inputs; round-1 post-mortem:
// the harness threshold is 2% of max|ref|, dtype-independent — round-0's bf16
// assumption produced NaN by misreading fp32 buffers).
// ws layout: Q fp32 [B][N][16] (2MB) | K fp32 [B][16][N] (2MB) | V bf16 [B][N][128] (8MB)
// Round 1: correct VALU flash-attention baseline. MFMA next.

static constexpr int Bb  = 8;
static constexpr int Cc  = 128;
static constexpr int Nn  = 4096;
static constexpr int CQ  = 16;
static constexpr int QR  = 32;    // query rows per block (kernel 2)
static constexpr int MCk = 128;   // key/value chunk (kernel 2)

__device__ __forceinline__ float bfu(unsigned short u) {
    union { unsigned int i; float f; } z; z.i = ((unsigned int)u) << 16; return z.f;
}

// ---------------- Kernel 1: QKV projection ----------------
// grid (N/64, B), block 256.
__global__ __launch_bounds__(256) void qkv_kernel(
    const float* __restrict__ x,
    const float* __restrict__ Wq,
    const float* __restrict__ Wk,
    const float* __restrict__ Wv,
    float* __restrict__ qw, float* __restrict__ kw,
    __hip_bfloat16* __restrict__ vw)
{
    const int b  = blockIdx.y;
    const int n0 = blockIdx.x * 64;
    const int t  = threadIdx.x;

    __shared__ float xs[Cc][64];    // 32 KB: x[b, :, n0:n0+64] staged
    __shared__ float wq_s[CQ * Cc]; // 8 KB
    __shared__ float wk_s[CQ * Cc]; // 8 KB

    for (int i = t; i < Cc * 64; i += 256) {
        int c = i >> 6, n = i & 63;
        xs[c][n] = x[((size_t)(b * Cc + c)) * Nn + n0 + n];
    }
    for (int i = t; i < CQ * Cc; i += 256) {
        wq_s[i] = Wq[i];
        wk_s[i] = Wk[i];
    }
    __syncthreads();

    // q and k: 64 n x 16 o each
    for (int idx = t; idx < 2048; idx += 256) {
        int which = idx >> 10;           // 0 = q, 1 = k
        int j = idx & 1023;
        int n = j >> 4, o = j & 15;
        const float* w = (which ? wk_s : wq_s) + o * Cc;
        float acc = 0.f;
        #pragma unroll 8
        for (int c = 0; c < Cc; ++c) acc += w[c] * xs[c][n];
        if (which == 0) qw[((size_t)b * Nn + n0 + n) * CQ + o] = acc;
        else            kw[((size_t)b * CQ + o) * Nn + n0 + n] = acc;
    }

    // v: 64 n x 128 c_out  (Wv read from global; 64KB fp32 fits L2/L1)
    for (int idx = t; idx < 64 * Cc; idx += 256) {
        int n = idx >> 7, co = idx & 127;
        const float* w = Wv + co * Cc;
        float acc = 0.f;
        #pragma unroll 8
        for (int c = 0; c < Cc; ++c) acc += w[c] * xs[c][n];
        vw[((size_t)b * Nn + n0 + n) * Cc + co] = __float2bfloat16(acc);
    }
}

// ---------------- Kernel 2: flash attention + residual ----------------
// grid (N/QR, B), block 256.
// Thread tile: 4 rows x 4 channels of the O accumulator.
__global__ __launch_bounds__(256) void attn_kernel(
    const float* __restrict__ x,
    const float* __restrict__ qw, const float* __restrict__ kw,
    const __hip_bfloat16* __restrict__ vw,
    const float* __restrict__ gamma,
    float* __restrict__ out)
{
    const int b  = blockIdx.y;
    const int n0 = blockIdx.x * QR;
    const int t  = threadIdx.x;

    __shared__ float qs[QR * CQ];          // 2 KB
    __shared__ float Kc[CQ][MCk];          // 8 KB
    __shared__ float P[QR][MCk + 1];       // 16.5 KB, +1 pad: conflict-free row scans
    __shared__ float alpha_s[QR];
    __shared__ float l_s[QR];

    for (int i = t; i < QR * CQ; i += 256)
        qs[i] = qw[((size_t)b * Nn + n0) * CQ + i];

    const int cgrp = t & 31;   const int c0 = cgrp * 4;   // channels c0..c0+3
    const int rgrp = t >> 5;   const int r0 = rgrp * 4;   // rows r0..r0+3

    float O[4][4];
    #pragma unroll
    for (int i = 0; i < 4; ++i)
        #pragma unroll
        for (int j = 0; j < 4; ++j) O[i][j] = 0.f;

    // per-row online-softmax state, owned by threads t < QR (row r = t)
    float m_run = -3e38f, l_run = 0.f;

    for (int m0 = 0; m0 < Nn; m0 += MCk) {
        __syncthreads();   // previous chunk's acc done -> safe to overwrite Kc/P
        // stage K chunk (coalesced: m contiguous)
        for (int i = t; i < CQ * MCk; i += 256) {
            int o = i >> 7, mm = i & 127;
            Kc[o][mm] = kw[((size_t)b * CQ + o) * Nn + m0 + mm];
        }
        __syncthreads();
        // S = q . k  -> P
        for (int i = t; i < QR * MCk; i += 256) {
            int r = i >> 7, mm = i & 127;
            const float* q = qs + r * CQ;
            float acc = 0.f;
            #pragma unroll
            for (int o = 0; o < CQ; ++o) acc += q[o] * Kc[o][mm];
            P[r][mm] = acc;
        }
        __syncthreads();
        // online-softmax stats: one thread per row
        if (t < QR) {
            const int r = t;
            float cm = -3e38f;
            for (int mm = 0; mm < MCk; ++mm) cm = fmaxf(cm, P[r][mm]);
            float m_new = fmaxf(m_run, cm);
            float alpha = __expf(m_run - m_new);
            float sum = 0.f;
            for (int mm = 0; mm < MCk; ++mm) {
                float p = __expf(P[r][mm] - m_new);
                P[r][mm] = p;
                sum += p;
            }
            l_run = l_run * alpha + sum;
            m_run = m_new;
            alpha_s[r] = alpha;
        }
        __syncthreads();
        // O = alpha*O + P_chunk . V_chunk
        {
            float al[4];
            #pragma unroll
            for (int i = 0; i < 4; ++i) al[i] = alpha_s[r0 + i];
            #pragma unroll
            for (int i = 0; i < 4; ++i)
                #pragma unroll
                for (int j = 0; j < 4; ++j) O[i][j] *= al[i];

            const __hip_bfloat16* vbase = vw + ((size_t)b * Nn + m0) * Cc + c0;
            #pragma unroll 4
            for (int mm = 0; mm < MCk; ++mm) {
                uint2 vv = *reinterpret_cast<const uint2*>(vbase + (size_t)mm * Cc);
                float v0 = bfu(vv.x & 0xffffu), v1 = bfu(vv.x >> 16);
                float v2 = bfu(vv.y & 0xffffu), v3 = bfu(vv.y >> 16);
                #pragma unroll
                for (int i = 0; i < 4; ++i) {
                    float p = P[r0 + i][mm];   // wave-uniform -> LDS broadcast
                    O[i][0] += p * v0;  O[i][1] += p * v1;
                    O[i][2] += p * v2;  O[i][3] += p * v3;
                }
            }
        }
    }
    if (t < QR) l_s[t] = l_run;
    __syncthreads();

    const float g = gamma[0];
    float linv[4];
    #pragma unroll
    for (int i = 0; i < 4; ++i) linv[i] = 1.0f / l_s[r0 + i];

    // out[b][c][n] = x + gamma * O^T ; 4 consecutive n as one 16B store
    #pragma unroll
    for (int j = 0; j < 4; ++j) {
        int c = c0 + j;
        size_t base = ((size_t)b * Cc + c) * Nn + n0 + r0;
        float4 xv = *reinterpret_cast<const float4*>(x + base);
        float4 ov;
        ov.x = xv.x + g * O[0][j] * linv[0];
        ov.y = xv.y + g * O[1][j] * linv[1];
        ov.z = xv.z + g * O[2][j] * linv[2];
        ov.w = xv.w + g * O[3][j] * linv[3];
        *reinterpret_cast<float4*>(out + base) = ov;
    }
}

extern "C" void kernel_launch(void* const* d_in, const int* in_sizes, int n_in,
                              void* d_out, int out_size, void* d_ws, size_t ws_size,
                              hipStream_t stream) {
    const float* x  = (const float*)d_in[0];
    const float* Wq = (const float*)d_in[1];
    const float* Wk = (const float*)d_in[2];
    const float* Wv = (const float*)d_in[3];
    const float* gm = (const float*)d_in[4];

    float* qw = (float*)d_ws;                          // [B][N][16]  fp32, 2MB
    float* kw = qw + (size_t)Bb * Nn * CQ;             // [B][16][N]  fp32, 2MB
    __hip_bfloat16* vw = (__hip_bfloat16*)(kw + (size_t)Bb * CQ * Nn);  // [B][N][128] bf16, 8MB

    qkv_kernel<<<dim3(Nn / 64, Bb), 256, 0, stream>>>(x, Wq, Wk, Wv, qw, kw, vw);
    attn_kernel<<<dim3(Nn / QR, Bb), 256, 0, stream>>>(x, qw, kw, vw, gm,
                                                       (float*)d_out);
}

// Round 4
// 224.417 us; speedup vs baseline: 6.1994x; 6.1994x over previous
//
#include <hip/hip_runtime.h>
#include <hip/hip_bf16.h>

// Conv_SelfAttn — B=8, C=128, N=4096, C_QK=16. fp32 in/out.
// Round 4: round-3 full-MFMA design, compile fix only (hilo by value —
// clang cannot bind non-const refs to ext_vector_type elements).
//
// Layout assumptions (32x32x16_bf16):
//   C/D: col = lane&31, row = (reg&3) + 8*(reg>>2) + 4*(lane>>5)   [m74/m101 verified]
//   A  : m  = lane&31, k = 8*(lane>>5) + j (j=0..7 contiguous)     [by analogy w/ m89]
//   B  : n  = lane&31, k = 8*(lane>>5) + j
//
// ws: qw fp32 [B][N][16] | kw fp32 [B][N][16] | vw bf16 [B][C][N] (V^T)

typedef __bf16 bf16x8 __attribute__((ext_vector_type(8)));
typedef __bf16 bf16x4 __attribute__((ext_vector_type(4)));
typedef float  f32x16 __attribute__((ext_vector_type(16)));

static constexpr int Bb = 8, Cc = 128, Nn = 4096, CQ = 16;

__device__ __forceinline__ f32x16 mfma32(bf16x8 a, bf16x8 b, f32x16 c) {
    return __builtin_amdgcn_mfma_f32_32x32x16_bf16(a, b, c, 0, 0, 0);
}
struct HL { __bf16 h, l; };
__device__ __forceinline__ HL hilo(float f) {
    HL r;
    r.h = (__bf16)f;
    r.l = (__bf16)(f - (float)r.h);
    return r;
}

// ---------------- Kernel 1: QKV projection (MFMA) ----------------
// grid (N/64, B), 256 threads. Per block: x-tile 128ci x 64n.
__global__ __launch_bounds__(256) void qkv_kernel(
    const float* __restrict__ x, const float* __restrict__ Wq,
    const float* __restrict__ Wk, const float* __restrict__ Wv,
    float* __restrict__ qw, float* __restrict__ kw, __bf16* __restrict__ vw)
{
    const int b = blockIdx.y, n0 = blockIdx.x * 64, t = threadIdx.x;
    const int wave = t >> 6, lane = t & 63, lr = lane & 31, lq = lane >> 5;

    __shared__ __bf16 xh[64][136], xl[64][136];      // x^T tiles (n-major), hi/lo
    __shared__ __bf16 wqh[32][136], wql[32][136];    // [Wq;Wk] stacked, hi/lo
    __shared__ __bf16 wvh[128][136];                 // Wv hi

    // stage x (coalesced read along n, transposed 2B writes)
    {
        const int n = t & 63, cib = t >> 6;
        #pragma unroll 4
        for (int i = 0; i < 32; ++i) {
            int ci = cib + i * 4;
            float v = x[((size_t)(b * Cc + ci)) * Nn + n0 + n];
            HL z = hilo(v);
            xh[n][ci] = z.h; xl[n][ci] = z.l;
        }
    }
    // stage Wq, Wk hi/lo (rows: q=0..15, k=16..31)
    #pragma unroll
    for (int i = 0; i < 8; ++i) {
        int idx = t + i * 256;
        int o = idx >> 7, ci = idx & 127;
        HL zq = hilo(Wq[idx]);
        wqh[o][ci] = zq.h; wql[o][ci] = zq.l;
        HL zk = hilo(Wk[idx]);
        wqh[16 + o][ci] = zk.h; wql[16 + o][ci] = zk.l;
    }
    // stage Wv hi (float4 reads)
    #pragma unroll
    for (int i = 0; i < 16; ++i) {
        int flat = t * 4 + i * 1024;
        float4 w4 = *(const float4*)(Wv + flat);
        int c = flat >> 7, ci0 = flat & 127;
        bf16x4 h4 = { (__bf16)w4.x, (__bf16)w4.y, (__bf16)w4.z, (__bf16)w4.w };
        *(bf16x4*)&wvh[c][ci0] = h4;
    }
    __syncthreads();

    // QK: waves 0,1 (nh = wave). C-tile rows = o' (q 0..15, k 16..31), cols = n.
    if (wave < 2) {
        const int nh = wave;
        f32x16 acc = {};
        #pragma unroll
        for (int ks = 0; ks < 8; ++ks) {
            bf16x8 ah = *(const bf16x8*)&wqh[lr][ks * 16 + lq * 8];
            bf16x8 al = *(const bf16x8*)&wql[lr][ks * 16 + lq * 8];
            bf16x8 bh = *(const bf16x8*)&xh[nh * 32 + lr][ks * 16 + lq * 8];
            bf16x8 bl = *(const bf16x8*)&xl[nh * 32 + lr][ks * 16 + lq * 8];
            acc = mfma32(ah, bh, acc);
            acc = mfma32(al, bh, acc);
            acc = mfma32(ah, bl, acc);
        }
        const int n = n0 + nh * 32 + lr;
        #pragma unroll
        for (int r = 0; r < 16; ++r) {
            int op = (r & 3) + 8 * (r >> 2) + 4 * lq;
            if (op < 16) qw[((size_t)(b * Nn + n)) * CQ + op] = acc[r];
            else         kw[((size_t)(b * Nn + n)) * CQ + (op - 16)] = acc[r];
        }
    }
    // V tiles: 8 C-tiles (ct 0..3 x nh 0..1) distributed for balance
    {
        int tl[3][2]; int nt;
        if      (wave == 0) { tl[0][0]=2; tl[0][1]=0; nt=1; }
        else if (wave == 1) { tl[0][0]=2; tl[0][1]=1; nt=1; }
        else if (wave == 2) { tl[0][0]=0; tl[0][1]=0; tl[1][0]=1; tl[1][1]=0; tl[2][0]=3; tl[2][1]=0; nt=3; }
        else                { tl[0][0]=0; tl[0][1]=1; tl[1][0]=1; tl[1][1]=1; tl[2][0]=3; tl[2][1]=1; nt=3; }
        for (int ti = 0; ti < nt; ++ti) {
            const int ct = tl[ti][0], nh = tl[ti][1];
            f32x16 acc = {};
            #pragma unroll
            for (int ks = 0; ks < 8; ++ks) {
                bf16x8 a  = *(const bf16x8*)&wvh[ct * 32 + lr][ks * 16 + lq * 8];
                bf16x8 bh = *(const bf16x8*)&xh[nh * 32 + lr][ks * 16 + lq * 8];
                acc = mfma32(a, bh, acc);
            }
            const int n = n0 + nh * 32 + lr;
            #pragma unroll
            for (int r = 0; r < 16; ++r) {
                int c = (r & 3) + 8 * (r >> 2) + 4 * lq + ct * 32;
                vw[((size_t)(b * Cc + c)) * Nn + n] = (__bf16)acc[r];
            }
        }
    }
}

// ---------------- Kernel 2: MFMA flash attention + residual ----------------
// grid (N/128, B), 256 threads (4 waves x 32 queries). Key chunk Mc=64.
__global__ __launch_bounds__(256) void attn_kernel(
    const float* __restrict__ x, const float* __restrict__ qw,
    const float* __restrict__ kw, const __bf16* __restrict__ vw,
    const float* __restrict__ gamma, float* __restrict__ out)
{
    const int b = blockIdx.y, n0b = blockIdx.x * 128, t = threadIdx.x;
    const int wave = t >> 6, lane = t & 63, lr = lane & 31, lq = lane >> 5;

    __shared__ __bf16 qT[128][40];       // [n][ hi:0..15 | lo:16..31 | pad ]
    __shared__ __bf16 kT[64][40];        // [key][ hi | lo | pad ]
    __shared__ __bf16 vT[128][72];       // [c][m 0..63 | pad]
    __shared__ __bf16 Pl[4][32][72];     // per-wave P^T: [n][m]

    // stage Q once (hi/lo)
    #pragma unroll
    for (int i = 0; i < 2; ++i) {
        int idx = t + i * 256;
        int n = idx >> 2, og = idx & 3;
        float4 q4 = *(const float4*)(qw + ((size_t)(b * Nn + n0b + n)) * CQ + og * 4);
        HL z0 = hilo(q4.x), z1 = hilo(q4.y), z2 = hilo(q4.z), z3 = hilo(q4.w);
        bf16x4 h = { z0.h, z1.h, z2.h, z3.h };
        bf16x4 l = { z0.l, z1.l, z2.l, z3.l };
        *(bf16x4*)&qT[n][og * 4] = h;
        *(bf16x4*)&qT[n][16 + og * 4] = l;
    }

    // register-buffered K/V chunk staging
    const int vc = t >> 3, vs = t & 7;   // V: rows c = vc + 32i, 16B segment vs
    const int kr = t >> 2, kg = t & 3;   // K: row, float4 group
    uint4 vreg[4]; float4 kreg;

    auto load_chunk = [&](int m0) {
        #pragma unroll
        for (int i = 0; i < 4; ++i)
            vreg[i] = *(const uint4*)(vw + ((size_t)(b * Cc + vc + 32 * i)) * Nn + m0 + vs * 8);
        kreg = *(const float4*)(kw + ((size_t)(b * Nn + m0 + kr)) * CQ + kg * 4);
    };
    auto store_chunk = [&]() {
        #pragma unroll
        for (int i = 0; i < 4; ++i)
            *(uint4*)&vT[vc + 32 * i][vs * 8] = vreg[i];
        HL z0 = hilo(kreg.x), z1 = hilo(kreg.y), z2 = hilo(kreg.z), z3 = hilo(kreg.w);
        bf16x4 h = { z0.h, z1.h, z2.h, z3.h };
        bf16x4 l = { z0.l, z1.l, z2.l, z3.l };
        *(bf16x4*)&kT[kr][kg * 4] = h;
        *(bf16x4*)&kT[kr][16 + kg * 4] = l;
    };

    load_chunk(0);
    store_chunk();
    __syncthreads();

    const bf16x8 qhi = *(const bf16x8*)&qT[wave * 32 + lr][lq * 8];
    const bf16x8 qlo = *(const bf16x8*)&qT[wave * 32 + lr][16 + lq * 8];

    f32x16 acc[4] = {{}, {}, {}, {}};
    float m_run = -3e38f, l_run = 0.f;

    for (int it = 0; it < 64; ++it) {
        load_chunk((it < 63 ? it + 1 : 63) * 64);   // prefetch next (clamped)

        // S^T = K * Q^T : two 32-key tiles, hi/lo (3 MFMAs each)
        f32x16 s0 = {}, s1 = {};
        {
            bf16x8 kh = *(const bf16x8*)&kT[lr][lq * 8];
            bf16x8 kl = *(const bf16x8*)&kT[lr][16 + lq * 8];
            s0 = mfma32(kh, qhi, s0); s0 = mfma32(kl, qhi, s0); s0 = mfma32(kh, qlo, s0);
            kh = *(const bf16x8*)&kT[32 + lr][lq * 8];
            kl = *(const bf16x8*)&kT[32 + lr][16 + lq * 8];
            s1 = mfma32(kh, qhi, s1); s1 = mfma32(kl, qhi, s1); s1 = mfma32(kh, qlo, s1);
        }

        // online softmax (each lane owns one query col n = lr; lane pair via xor-32)
        float cmax = -3e38f;
        #pragma unroll
        for (int r = 0; r < 16; ++r) { cmax = fmaxf(cmax, s0[r]); cmax = fmaxf(cmax, s1[r]); }
        cmax = fmaxf(cmax, __shfl_xor(cmax, 32));
        const float mnew = fmaxf(m_run, cmax);
        const float alpha = __expf(m_run - mnew);
        float p0[16], p1[16], csum = 0.f;
        #pragma unroll
        for (int r = 0; r < 16; ++r) {
            p0[r] = __expf(s0[r] - mnew); csum += p0[r];
            p1[r] = __expf(s1[r] - mnew); csum += p1[r];
        }
        csum += __shfl_xor(csum, 32);
        l_run = l_run * alpha + csum;
        m_run = mnew;
        #pragma unroll
        for (int ct = 0; ct < 4; ++ct)
            #pragma unroll
            for (int r = 0; r < 16; ++r) acc[ct][r] *= alpha;

        // write P^T (bf16) : m = (r&3) + 8*(r>>2) + 4*lq (+32 for tile 1)
        #pragma unroll
        for (int g = 0; g < 4; ++g) {
            bf16x4 a = { (__bf16)p0[4*g], (__bf16)p0[4*g+1], (__bf16)p0[4*g+2], (__bf16)p0[4*g+3] };
            *(bf16x4*)&Pl[wave][lr][lq * 4 + g * 8] = a;
            bf16x4 c4 = { (__bf16)p1[4*g], (__bf16)p1[4*g+1], (__bf16)p1[4*g+2], (__bf16)p1[4*g+3] };
            *(bf16x4*)&Pl[wave][lr][32 + lq * 4 + g * 8] = c4;
        }

        // O^T += V^T * P  (A = V^T frags, B = P frags; 4 k-steps x 4 c-tiles)
        bf16x8 pf[4];
        #pragma unroll
        for (int ks = 0; ks < 4; ++ks)
            pf[ks] = *(const bf16x8*)&Pl[wave][lr][ks * 16 + lq * 8];
        #pragma unroll
        for (int ct = 0; ct < 4; ++ct) {
            #pragma unroll
            for (int ks = 0; ks < 4; ++ks) {
                bf16x8 va = *(const bf16x8*)&vT[ct * 32 + lr][ks * 16 + lq * 8];
                acc[ct] = mfma32(va, pf[ks], acc[ct]);
            }
        }

        __syncthreads();
        store_chunk();
        __syncthreads();
    }

    const float g = gamma[0];
    const float linv = 1.0f / l_run;
    const int n = n0b + wave * 32 + lr;
    #pragma unroll
    for (int ct = 0; ct < 4; ++ct) {
        #pragma unroll
        for (int r = 0; r < 16; ++r) {
            int c = (r & 3) + 8 * (r >> 2) + 4 * lq + ct * 32;
            size_t idx = ((size_t)(b * Cc + c)) * Nn + n;
            out[idx] = x[idx] + g * acc[ct][r] * linv;
        }
    }
}

extern "C" void kernel_launch(void* const* d_in, const int* in_sizes, int n_in,
                              void* d_out, int out_size, void* d_ws, size_t ws_size,
                              hipStream_t stream) {
    const float* x  = (const float*)d_in[0];
    const float* Wq = (const float*)d_in[1];
    const float* Wk = (const float*)d_in[2];
    const float* Wv = (const float*)d_in[3];
    const float* gm = (const float*)d_in[4];

    float* qw = (float*)d_ws;                              // [B][N][16] fp32
    float* kw = qw + (size_t)Bb * Nn * CQ;                 // [B][N][16] fp32
    __bf16* vw = (__bf16*)(kw + (size_t)Bb * Nn * CQ);     // [B][C][N] bf16 (V^T)

    qkv_kernel<<<dim3(Nn / 64, Bb), 256, 0, stream>>>(x, Wq, Wk, Wv, qw, kw, vw);
    attn_kernel<<<dim3(Nn / 128, Bb), 256, 0, stream>>>(x, qw, kw, vw, gm,
                                                        (float*)d_out);
}